// Round 11
// baseline (373.552 us; speedup 1.0000x reference)
//
#include <hip/hip_runtime.h>

#define N_NODES   100000
#define N_PAD     100096           // 782 * 128
#define N_EDGES   1600000
#define IN_FEAT   64
#define HIDDEN    128
#define N_CLASSES 16
#define N_GRAPHS  512
#define MAXDEG    64               // Poisson(16): P(deg>=64) ~ e^-126, never

#define BIN_NODES 512              // nodes per bin (dst >> 9)
#define NBINS     196              // ceil(100000 / 512)
#define N_NODES_B (NBINS * BIN_NODES)   // 100352 (csr/cursor allocated size)
#define BINCAP    9000             // Poisson(8192) + ~9 sigma
#define EPB       2048             // edges per phase-1 block

typedef __attribute__((ext_vector_type(8))) unsigned short us8;   // 8 bf16
typedef __attribute__((ext_vector_type(8))) short s8v;            // mfma frag_ab
typedef __attribute__((ext_vector_type(4))) float f4v;            // mfma frag_cd

__device__ __forceinline__ unsigned short f2bf(float f) {
    unsigned u = __builtin_bit_cast(unsigned, f);
    unsigned r = u + 0x7FFFu + ((u >> 16) & 1u);    // RNE
    return (unsigned short)(r >> 16);
}
__device__ __forceinline__ float bf2f(unsigned short h) {
    unsigned u = ((unsigned)h) << 16;
    return __builtin_bit_cast(float, u);
}
__device__ __forceinline__ void acc8(float* a, us8 v) {
#pragma unroll
    for (int e = 0; e < 8; e++) a[e] += bf2f(v[e]);
}

// ---------------- CSR build phase 1: bin edges by dst>>9 ----------------

__global__ __launch_bounds__(512) void bin_kernel(const int* __restrict__ src,
                                                  const int* __restrict__ dst,
                                                  int* __restrict__ bin_cursor,
                                                  int2* __restrict__ binbuf) {
    __shared__ int hist[NBINS];
    __shared__ int base[NBINS];
    const int t = threadIdx.x;
    for (int i = t; i < NBINS; i += 512) hist[i] = 0;
    __syncthreads();

    const int e0 = blockIdx.x * EPB;
    int myb[4], mys[4], myd[4], myp[4];
#pragma unroll
    for (int j = 0; j < 4; j++) {
        int e = e0 + t + j * 512;
        if (e < N_EDGES) {
            myd[j] = dst[e];
            mys[j] = src[e];
            myb[j] = myd[j] >> 9;
        } else {
            myb[j] = -1; mys[j] = 0; myd[j] = 0;
        }
    }
#pragma unroll
    for (int j = 0; j < 4; j++)
        myp[j] = (myb[j] >= 0) ? atomicAdd(&hist[myb[j]], 1) : 0;
    __syncthreads();

    for (int i = t; i < NBINS; i += 512) {
        int h = hist[i];
        base[i] = (h > 0) ? atomicAdd(&bin_cursor[i], h) : 0;
    }
    __syncthreads();

#pragma unroll
    for (int j = 0; j < 4; j++) {
        if (myb[j] >= 0) {
            int pos = base[myb[j]] + myp[j];
            if (pos < BINCAP)
                binbuf[(size_t)myb[j] * BINCAP + pos] = make_int2(mys[j], myd[j]);
        }
    }
}

// ---------------- CSR build phase 2: per-bin scatter in LDS, coalesced writeout ------

__global__ __launch_bounds__(512) void build_kernel(const int2* __restrict__ binbuf,
                                                    const int* __restrict__ bin_cursor,
                                                    int* __restrict__ cursor,
                                                    int* __restrict__ csr) {
    __shared__ int lcur[BIN_NODES];                 // 2 KB
    __shared__ int lcsr[BIN_NODES * MAXDEG];        // 128 KB
    const int b = blockIdx.x, t = threadIdx.x;
    if (t < BIN_NODES) lcur[t] = 0;
    __syncthreads();

    int cnt = bin_cursor[b];
    if (cnt > BINCAP) cnt = BINCAP;
    const int2* __restrict__ eb = binbuf + (size_t)b * BINCAP;
    for (int i = t; i < cnt; i += 512) {
        int2 e = eb[i];
        int dl = e.y - b * BIN_NODES;               // 0..511
        int p = atomicAdd(&lcur[dl], 1);
        if (p < MAXDEG) lcsr[dl * MAXDEG + p] = e.x;
    }
    __syncthreads();

    // coalesced writeout: 32768 ints = 8192 int4
    int4* __restrict__ gout = reinterpret_cast<int4*>(csr + (size_t)b * BIN_NODES * MAXDEG);
    const int4* __restrict__ lin = reinterpret_cast<const int4*>(lcsr);
    for (int i = t; i < BIN_NODES * MAXDEG / 4; i += 512) gout[i] = lin[i];
    if (t < BIN_NODES) cursor[b * BIN_NODES + t] = lcur[t];
}

// ---------------- x -> bf16 (pad rows zeroed) ----------------

__global__ void convert_x_kernel(const float* __restrict__ x, ushort* __restrict__ xh) {
    const int flat = blockIdx.x * 256 + threadIdx.x;      // one us8 per thread
    const int row = flat >> 3;                             // 8 us8 per 64-feat row
    us8 w;
    if (row < N_NODES) {
        const float* p = x + (size_t)flat * 8;
        float4 v0 = *reinterpret_cast<const float4*>(p);
        float4 v1 = *reinterpret_cast<const float4*>(p + 4);
        w[0] = f2bf(v0.x); w[1] = f2bf(v0.y); w[2] = f2bf(v0.z); w[3] = f2bf(v0.w);
        w[4] = f2bf(v1.x); w[5] = f2bf(v1.y); w[6] = f2bf(v1.z); w[7] = f2bf(v1.w);
    } else {
#pragma unroll
        for (int e = 0; e < 8; e++) w[e] = 0;
    }
    reinterpret_cast<us8*>(xh)[flat] = w;
}

// ---------------- pack weights into MFMA fragment order (bf16) ----------------
// dst[((ks*8+ct)*64+lane)*8+j] = bf16( src[(ks*32+(lane>>4)*8+j)*128 + ct*16+(lane&15)] )

__global__ void pack_weights_kernel(const float* __restrict__ s0, const float* __restrict__ s1,
                                    const float* __restrict__ s2, const float* __restrict__ s3,
                                    const float* __restrict__ s4, const float* __restrict__ s5,
                                    ushort* __restrict__ Bpk) {
    const int flat = blockIdx.x * 256 + threadIdx.x;       // < 81920
    const float* src; int base;
    if      (flat < 8192)  { src = s0; base = 0; }
    else if (flat < 16384) { src = s1; base = 8192; }
    else if (flat < 32768) { src = s2; base = 16384; }
    else if (flat < 49152) { src = s3; base = 32768; }
    else if (flat < 65536) { src = s4; base = 49152; }
    else                   { src = s5; base = 65536; }
    const int local = flat - base;
    const int j    = local & 7;
    const int lane = (local >> 3) & 63;
    const int tile = local >> 9;
    const int ks = tile >> 3, ct = tile & 7;
    const int row = ks * 32 + ((lane >> 4) << 3) + j;
    const int col = (ct << 4) + (lane & 15);
    Bpk[flat] = f2bf(src[row * 128 + col]);
}

// ------- MERGED SAGE layer: gather-mean -> LDS A-tile -> MFMA -> act -> out ----------
// Phase A: standalone-aggregate shape (LPN contiguous lanes per node, 8-deep MLP),
// writing XOR-swizzled 16B chunks into a [128][K] LDS tile.
// Phase B: MFMA; A1 frags from LDS (swizzled ds_read_b128), A2 (self) + B from global
// (B is 32/64KB, L2-resident across all 782 blocks). 32KB LDS -> 4 blocks/CU, so
// gather of some blocks overlaps MFMA of others on the same CU.

template <int K, bool RELU>
__global__ __launch_bounds__(256, 4) void sage_layer(
        const ushort* __restrict__ feat,
        const int* __restrict__ cursor, const int* __restrict__ csr,
        const ushort* __restrict__ B1p, const ushort* __restrict__ B2p,
        const float* __restrict__ bias, ushort* __restrict__ out) {
    constexpr int KS  = K / 32;          // MFMA k-steps
    constexpr int NCH = K / 8;           // 16B chunks per row
    constexpr int LPN = K / 8;           // lanes per node in gather
    constexpr int NPP = 256 / LPN;       // nodes per gather pass
    __shared__ ushort A_lds[128 * K];    // K=128: 32KB, K=64: 16KB
    us8* __restrict__ A8 = reinterpret_cast<us8*>(A_lds);

    const int tid = threadIdx.x;
    const int r0 = blockIdx.x * 128;

    // ---- phase A: gather-mean of 128 rows into LDS ----
    {
        const int ch   = tid & (LPN - 1);        // chunk this lane owns
        const int slot = tid / LPN;
        const us8* __restrict__ f8 = reinterpret_cast<const us8*>(feat);
#pragma unroll
        for (int p = 0; p < 128 / NPP; p++) {
            const int rl = p * NPP + slot;       // local row 0..127
            const int n  = r0 + rl;
            const int start = n * MAXDEG;
            int cnt = cursor[n];
            if (cnt > MAXDEG) cnt = MAXDEG;

            float a[8] = {0.f, 0.f, 0.f, 0.f, 0.f, 0.f, 0.f, 0.f};
            int i = 0;
            for (; i + 8 <= cnt; i += 8) {
                int t0 = csr[start + i + 0], t1 = csr[start + i + 1];
                int t2 = csr[start + i + 2], t3 = csr[start + i + 3];
                int t4 = csr[start + i + 4], t5 = csr[start + i + 5];
                int t6 = csr[start + i + 6], t7 = csr[start + i + 7];
                us8 v0 = f8[(size_t)t0 * LPN + ch];
                us8 v1 = f8[(size_t)t1 * LPN + ch];
                us8 v2 = f8[(size_t)t2 * LPN + ch];
                us8 v3 = f8[(size_t)t3 * LPN + ch];
                us8 v4 = f8[(size_t)t4 * LPN + ch];
                us8 v5 = f8[(size_t)t5 * LPN + ch];
                us8 v6 = f8[(size_t)t6 * LPN + ch];
                us8 v7 = f8[(size_t)t7 * LPN + ch];
                acc8(a, v0); acc8(a, v1); acc8(a, v2); acc8(a, v3);
                acc8(a, v4); acc8(a, v5); acc8(a, v6); acc8(a, v7);
            }
            for (; i + 4 <= cnt; i += 4) {
                int t0 = csr[start + i + 0], t1 = csr[start + i + 1];
                int t2 = csr[start + i + 2], t3 = csr[start + i + 3];
                us8 v0 = f8[(size_t)t0 * LPN + ch];
                us8 v1 = f8[(size_t)t1 * LPN + ch];
                us8 v2 = f8[(size_t)t2 * LPN + ch];
                us8 v3 = f8[(size_t)t3 * LPN + ch];
                acc8(a, v0); acc8(a, v1); acc8(a, v2); acc8(a, v3);
            }
            for (; i < cnt; i++) {
                us8 v0 = f8[(size_t)csr[start + i] * LPN + ch];
                acc8(a, v0);
            }
            const float inv = 1.f / (float)(cnt > 0 ? cnt : 1);
            us8 w;
#pragma unroll
            for (int e = 0; e < 8; e++) w[e] = f2bf(a[e] * inv);
            A8[rl * NCH + (ch ^ (rl & 7))] = w;     // swizzled chunk
        }
    }
    __syncthreads();

    // ---- phase B: MFMA ----
    const int wave = tid >> 6, lane = tid & 63;
    const int rw = wave * 32 + (lane & 15);          // local row (A1 frag)
    const int rowbase = r0 + rw;
    const int koff = (lane >> 4) << 3;
    const int swz = rw & 7;                          // (rw+16)&7 == rw&7

    f4v acc[2][8];
#pragma unroll
    for (int rt = 0; rt < 2; rt++)
#pragma unroll
        for (int ct = 0; ct < 8; ct++) acc[rt][ct] = (f4v){0.f, 0.f, 0.f, 0.f};

    const s8v* __restrict__ Als = reinterpret_cast<const s8v*>(A_lds);
    const s8v* __restrict__ Bf1 = reinterpret_cast<const s8v*>(B1p);
    const s8v* __restrict__ Bf2 = reinterpret_cast<const s8v*>(B2p);
#pragma unroll
    for (int ks = 0; ks < KS; ks++) {
        const int c0 = ks * 4 + (lane >> 4);
        s8v a0 = Als[rw * NCH + (c0 ^ swz)];
        s8v a1 = Als[(rw + 16) * NCH + (c0 ^ swz)];
#pragma unroll
        for (int ct = 0; ct < 8; ct++) {
            s8v b = Bf1[(ks * 8 + ct) * 64 + lane];
            acc[0][ct] = __builtin_amdgcn_mfma_f32_16x16x32_bf16(a0, b, acc[0][ct], 0, 0, 0);
            acc[1][ct] = __builtin_amdgcn_mfma_f32_16x16x32_bf16(a1, b, acc[1][ct], 0, 0, 0);
        }
    }
#pragma unroll
    for (int ks = 0; ks < KS; ks++) {
        s8v s0 = *reinterpret_cast<const s8v*>(feat + (size_t)rowbase * K + ks * 32 + koff);
        s8v s1 = *reinterpret_cast<const s8v*>(feat + (size_t)(rowbase + 16) * K + ks * 32 + koff);
#pragma unroll
        for (int ct = 0; ct < 8; ct++) {
            s8v b = Bf2[(ks * 8 + ct) * 64 + lane];
            acc[0][ct] = __builtin_amdgcn_mfma_f32_16x16x32_bf16(s0, b, acc[0][ct], 0, 0, 0);
            acc[1][ct] = __builtin_amdgcn_mfma_f32_16x16x32_bf16(s1, b, acc[1][ct], 0, 0, 0);
        }
    }

    // epilogue: C/D layout col=lane&15, row=(lane>>4)*4+reg  [m89]
    const int colb = lane & 15;
    const int rowb = (lane >> 4) << 2;
#pragma unroll
    for (int rt = 0; rt < 2; rt++) {
#pragma unroll
        for (int ct = 0; ct < 8; ct++) {
            const int col = ct * 16 + colb;
            const float bb = bias[col];
#pragma unroll
            for (int j = 0; j < 4; j++) {
                int row = r0 + wave * 32 + rt * 16 + rowb + j;
                if (row < N_NODES) {
                    float v = acc[rt][ct][j] + bb;
                    if (RELU) v = fmaxf(v, 0.f);
                    out[(size_t)row * HIDDEN + col] = f2bf(v);
                }
            }
        }
    }
}

// ---------------- global mean pool (bf16 in, f32 out; one wave per graph) -------------

__global__ __launch_bounds__(256) void pool_bf(const ushort* __restrict__ h,
                                               const int* __restrict__ batch,
                                               float* __restrict__ g) {
    __shared__ int sb[5];
    const int g0 = blockIdx.x * 4;
    const int tid = threadIdx.x;
    if (tid <= 4) {
        int target = g0 + tid;
        int lo = 0, hi = N_NODES;
        while (lo < hi) {
            int mid = (lo + hi) >> 1;
            if (batch[mid] < target) lo = mid + 1; else hi = mid;
        }
        sb[tid] = lo;
    }
    __syncthreads();
    const int lg = tid >> 6;
    const int lane = tid & 63;
    const int s = sb[lg], e = sb[lg + 1];
    const int nsub = lane >> 4;
    const int cc = lane & 15;
    const us8* __restrict__ h8 = reinterpret_cast<const us8*>(h);

    float a[8] = {0.f, 0.f, 0.f, 0.f, 0.f, 0.f, 0.f, 0.f};
    int n = s + nsub;
    for (; n + 12 < e; n += 16) {
        us8 v0 = h8[(size_t)(n + 0) * 16 + cc];
        us8 v1 = h8[(size_t)(n + 4) * 16 + cc];
        us8 v2 = h8[(size_t)(n + 8) * 16 + cc];
        us8 v3 = h8[(size_t)(n + 12) * 16 + cc];
        acc8(a, v0); acc8(a, v1); acc8(a, v2); acc8(a, v3);
    }
    for (; n < e; n += 4) {
        us8 v0 = h8[(size_t)n * 16 + cc];
        acc8(a, v0);
    }
#pragma unroll
    for (int e2 = 0; e2 < 8; e2++) {
        a[e2] += __shfl_xor(a[e2], 16);
        a[e2] += __shfl_xor(a[e2], 32);
    }
    if (nsub == 0) {
        const int cnt = e - s;
        const float inv = 1.f / (float)(cnt > 0 ? cnt : 1);
        float4 w0 = make_float4(a[0] * inv, a[1] * inv, a[2] * inv, a[3] * inv);
        float4 w1 = make_float4(a[4] * inv, a[5] * inv, a[6] * inv, a[7] * inv);
        float* dst = g + (size_t)(g0 + lg) * HIDDEN + cc * 8;
        *reinterpret_cast<float4*>(dst) = w0;
        *reinterpret_cast<float4*>(dst + 4) = w1;
    }
}

// ---------------- output head: out = g @ W_out + b_out (f32 exact) ----------------

__global__ void head_kernel(const float* __restrict__ g, const float* __restrict__ W,
                            const float* __restrict__ b, float* __restrict__ out) {
    const int gid = blockIdx.x * 4 + (threadIdx.x >> 4);
    const int f = threadIdx.x & 15;
    if (gid >= N_GRAPHS) return;
    float acc = b[f];
    for (int k = 0; k < HIDDEN; k++)
        acc += g[(size_t)gid * HIDDEN + k] * W[k * N_CLASSES + f];
    out[(size_t)gid * N_CLASSES + f] = acc;
}

// ---------------- launch ----------------

extern "C" void kernel_launch(void* const* d_in, const int* in_sizes, int n_in,
                              void* d_out, int out_size, void* d_ws, size_t ws_size,
                              hipStream_t stream) {
    const float* x    = (const float*)d_in[0];
    const int* eidx   = (const int*)d_in[1];
    const int* batch  = (const int*)d_in[2];
    const float* Wl1  = (const float*)d_in[3];
    const float* bl1  = (const float*)d_in[4];
    const float* Wr1  = (const float*)d_in[5];
    const float* Wl2  = (const float*)d_in[6];
    const float* bl2  = (const float*)d_in[7];
    const float* Wr2  = (const float*)d_in[8];
    const float* Wl3  = (const float*)d_in[9];
    const float* bl3  = (const float*)d_in[10];
    const float* Wr3  = (const float*)d_in[11];
    const float* Wout = (const float*)d_in[12];
    const float* bout = (const float*)d_in[13];
    float* out = (float*)d_out;

    const int* esrc = eidx;
    const int* edst = eidx + N_EDGES;

    char* ws = (char*)d_ws;
    size_t o = 0;
    int*  bin_cursor = (int*)(ws + o);  o += 256 * 4;                        // zeroed
    int*  cursor     = (int*)(ws + o);  o += (size_t)N_NODES_B * 4;
    int*  csr        = (int*)(ws + o);  o += (size_t)N_NODES_B * MAXDEG * 4; // 25.7 MB
    int2* binbuf     = (int2*)(ws + o); o += (size_t)NBINS * BINCAP * 8;     // 14.1 MB
    o = (o + 255) & ~(size_t)255;
    ushort* xh   = (ushort*)(ws + o); o += (size_t)N_PAD * IN_FEAT * 2;
    ushort* h1b  = (ushort*)(ws + o); o += (size_t)N_PAD * HIDDEN * 2;
    ushort* h2b  = (ushort*)(ws + o); o += (size_t)N_PAD * HIDDEN * 2;
    ushort* Bpk  = (ushort*)(ws + o); o += (size_t)81920 * 2;
    float*  g    = (float*)(ws + o);  o += (size_t)N_GRAPHS * HIDDEN * 4;

    hipMemsetAsync(bin_cursor, 0, 256 * 4, stream);

    bin_kernel<<<(N_EDGES + EPB - 1) / EPB, 512, 0, stream>>>(esrc, edst, bin_cursor, binbuf);
    build_kernel<<<NBINS, 512, 0, stream>>>(binbuf, bin_cursor, cursor, csr);

    pack_weights_kernel<<<320, 256, 0, stream>>>(Wl1, Wr1, Wl2, Wr2, Wl3, Wr3, Bpk);
    convert_x_kernel<<<(N_PAD * IN_FEAT / 8) / 256, 256, 0, stream>>>(x, xh);

    ushort* Wl1p = Bpk + 0,     *Wr1p = Bpk + 8192;
    ushort* Wl2p = Bpk + 16384, *Wr2p = Bpk + 32768;
    ushort* Wl3p = Bpk + 49152, *Wr3p = Bpk + 65536;

    const int GB = N_PAD / 128;                       // 782

    // one merged kernel per layer: gather->LDS->MFMA->act->out
    sage_layer<IN_FEAT, true><<<GB, 256, 0, stream>>>(xh, cursor, csr, Wl1p, Wr1p, bl1, h1b);
    sage_layer<HIDDEN, true><<<GB, 256, 0, stream>>>(h1b, cursor, csr, Wl2p, Wr2p, bl2, h2b);
    sage_layer<HIDDEN, false><<<GB, 256, 0, stream>>>(h2b, cursor, csr, Wl3p, Wr3p, bl3, h1b);

    // pool + head
    pool_bf<<<N_GRAPHS / 4, 256, 0, stream>>>(h1b, batch, g);
    head_kernel<<<N_GRAPHS / 4, 64, 0, stream>>>(g, Wout, bout, out);
}

// Round 12
// 351.324 us; speedup vs baseline: 1.0633x; 1.0633x over previous
//
#include <hip/hip_runtime.h>

#define N_NODES   100000
#define N_PAD     100096           // 782 * 128
#define N_EDGES   1600000
#define IN_FEAT   64
#define HIDDEN    128
#define N_CLASSES 16
#define N_GRAPHS  512
#define MAXDEG    64               // Poisson(16): P(deg>=64) ~ e^-126, never
#define PSEG      4                // segments per graph in edge_pool

#define BIN_NODES 512              // nodes per bin (dst >> 9)
#define NBINS     196              // ceil(100000 / 512)
#define N_NODES_B (NBINS * BIN_NODES)   // 100352 (csr/cursor allocated size)
#define BINCAP    9000             // Poisson(8192) + ~9 sigma
#define EPB       2048             // edges per phase-1 block

typedef __attribute__((ext_vector_type(8))) unsigned short us8;   // 8 bf16
typedef __attribute__((ext_vector_type(8))) short s8v;            // mfma frag_ab
typedef __attribute__((ext_vector_type(4))) float f4v;            // mfma frag_cd

__device__ __forceinline__ unsigned short f2bf(float f) {
    unsigned u = __builtin_bit_cast(unsigned, f);
    unsigned r = u + 0x7FFFu + ((u >> 16) & 1u);    // RNE
    return (unsigned short)(r >> 16);
}
__device__ __forceinline__ float bf2f(unsigned short h) {
    unsigned u = ((unsigned)h) << 16;
    return __builtin_bit_cast(float, u);
}
__device__ __forceinline__ void acc8(float* a, us8 v) {
#pragma unroll
    for (int e = 0; e < 8; e++) a[e] += bf2f(v[e]);
}

// ---------------- CSR build phase 1: bin edges by dst>>9 ----------------

__global__ __launch_bounds__(512) void bin_kernel(const int* __restrict__ src,
                                                  const int* __restrict__ dst,
                                                  int* __restrict__ bin_cursor,
                                                  int2* __restrict__ binbuf) {
    __shared__ int hist[NBINS];
    __shared__ int base[NBINS];
    const int t = threadIdx.x;
    for (int i = t; i < NBINS; i += 512) hist[i] = 0;
    __syncthreads();

    const int e0 = blockIdx.x * EPB;
    int myb[4], mys[4], myd[4], myp[4];
#pragma unroll
    for (int j = 0; j < 4; j++) {
        int e = e0 + t + j * 512;
        if (e < N_EDGES) {
            myd[j] = dst[e];
            mys[j] = src[e];
            myb[j] = myd[j] >> 9;
        } else {
            myb[j] = -1; mys[j] = 0; myd[j] = 0;
        }
    }
#pragma unroll
    for (int j = 0; j < 4; j++)
        myp[j] = (myb[j] >= 0) ? atomicAdd(&hist[myb[j]], 1) : 0;
    __syncthreads();

    for (int i = t; i < NBINS; i += 512) {
        int h = hist[i];
        base[i] = (h > 0) ? atomicAdd(&bin_cursor[i], h) : 0;
    }
    __syncthreads();

#pragma unroll
    for (int j = 0; j < 4; j++) {
        if (myb[j] >= 0) {
            int pos = base[myb[j]] + myp[j];
            if (pos < BINCAP)
                binbuf[(size_t)myb[j] * BINCAP + pos] = make_int2(mys[j], myd[j]);
        }
    }
}

// ---------------- CSR build phase 2: per-bin scatter in LDS, coalesced writeout ------

__global__ __launch_bounds__(512) void build_kernel(const int2* __restrict__ binbuf,
                                                    const int* __restrict__ bin_cursor,
                                                    int* __restrict__ cursor,
                                                    int* __restrict__ csr) {
    __shared__ int lcur[BIN_NODES];                 // 2 KB
    __shared__ int lcsr[BIN_NODES * MAXDEG];        // 128 KB
    const int b = blockIdx.x, t = threadIdx.x;
    if (t < BIN_NODES) lcur[t] = 0;
    __syncthreads();

    int cnt = bin_cursor[b];
    if (cnt > BINCAP) cnt = BINCAP;
    const int2* __restrict__ eb = binbuf + (size_t)b * BINCAP;
    for (int i = t; i < cnt; i += 512) {
        int2 e = eb[i];
        int dl = e.y - b * BIN_NODES;               // 0..511
        int p = atomicAdd(&lcur[dl], 1);
        if (p < MAXDEG) lcsr[dl * MAXDEG + p] = e.x;
    }
    __syncthreads();

    // coalesced writeout: 32768 ints = 8192 int4
    int4* __restrict__ gout = reinterpret_cast<int4*>(csr + (size_t)b * BIN_NODES * MAXDEG);
    const int4* __restrict__ lin = reinterpret_cast<const int4*>(lcsr);
    for (int i = t; i < BIN_NODES * MAXDEG / 4; i += 512) gout[i] = lin[i];
    if (t < BIN_NODES) cursor[b * BIN_NODES + t] = lcur[t];
}

// ---------------- x -> bf16 (pad rows zeroed) ----------------

__global__ void convert_x_kernel(const float* __restrict__ x, ushort* __restrict__ xh) {
    const int flat = blockIdx.x * 256 + threadIdx.x;      // one us8 per thread
    const int row = flat >> 3;                             // 8 us8 per 64-feat row
    us8 w;
    if (row < N_NODES) {
        const float* p = x + (size_t)flat * 8;
        float4 v0 = *reinterpret_cast<const float4*>(p);
        float4 v1 = *reinterpret_cast<const float4*>(p + 4);
        w[0] = f2bf(v0.x); w[1] = f2bf(v0.y); w[2] = f2bf(v0.z); w[3] = f2bf(v0.w);
        w[4] = f2bf(v1.x); w[5] = f2bf(v1.y); w[6] = f2bf(v1.z); w[7] = f2bf(v1.w);
    } else {
#pragma unroll
        for (int e = 0; e < 8; e++) w[e] = 0;
    }
    reinterpret_cast<us8*>(xh)[flat] = w;
}

// ---------------- pack weights (layers 1,2 only) into MFMA fragment order ------------
// dst[((ks*8+ct)*64+lane)*8+j] = bf16( src[(ks*32+(lane>>4)*8+j)*128 + ct*16+(lane&15)] )

__global__ void pack_weights_kernel(const float* __restrict__ s0, const float* __restrict__ s1,
                                    const float* __restrict__ s2, const float* __restrict__ s3,
                                    ushort* __restrict__ Bpk) {
    const int flat = blockIdx.x * 256 + threadIdx.x;       // < 49152
    const float* src; int base;
    if      (flat < 8192)  { src = s0; base = 0; }
    else if (flat < 16384) { src = s1; base = 8192; }
    else if (flat < 32768) { src = s2; base = 16384; }
    else                   { src = s3; base = 32768; }
    const int local = flat - base;
    const int j    = local & 7;
    const int lane = (local >> 3) & 63;
    const int tile = local >> 9;
    const int ks = tile >> 3, ct = tile & 7;
    const int row = ks * 32 + ((lane >> 4) << 3) + j;
    const int col = (ct << 4) + (lane & 15);
    Bpk[flat] = f2bf(src[row * 128 + col]);
}

// ------- aggregation (bf16 gather-mean, us8 lanes, 16-deep MLP) — R10 proven shape ----

template <int D>
__global__ __launch_bounds__(256, 4) void aggregate_bf(
        const ushort* __restrict__ feat, const int* __restrict__ cursor,
        const int* __restrict__ csr, ushort* __restrict__ aggout) {
    constexpr int LPN = D / 8;           // lanes per node (one us8 each)
    constexpr int NPB = 256 / LPN;
    const int tid  = threadIdx.x;
    const int lane = tid & (LPN - 1);
    const int n    = blockIdx.x * NPB + tid / LPN;
    if (n >= N_NODES) return;
    const int start = n * MAXDEG;
    int cnt = cursor[n];
    if (cnt > MAXDEG) cnt = MAXDEG;
    const us8* __restrict__ f8 = reinterpret_cast<const us8*>(feat);

    float a[8] = {0.f, 0.f, 0.f, 0.f, 0.f, 0.f, 0.f, 0.f};
    int i = 0;
    for (; i + 16 <= cnt; i += 16) {
        int t[16];
#pragma unroll
        for (int u = 0; u < 16; u++) t[u] = csr[start + i + u];
        us8 v[16];
#pragma unroll
        for (int u = 0; u < 16; u++) v[u] = f8[(size_t)t[u] * LPN + lane];
#pragma unroll
        for (int u = 0; u < 16; u++) acc8(a, v[u]);
    }
    for (; i + 8 <= cnt; i += 8) {
        int t[8];
#pragma unroll
        for (int u = 0; u < 8; u++) t[u] = csr[start + i + u];
        us8 v[8];
#pragma unroll
        for (int u = 0; u < 8; u++) v[u] = f8[(size_t)t[u] * LPN + lane];
#pragma unroll
        for (int u = 0; u < 8; u++) acc8(a, v[u]);
    }
    for (; i + 4 <= cnt; i += 4) {
        int t0 = csr[start + i + 0], t1 = csr[start + i + 1];
        int t2 = csr[start + i + 2], t3 = csr[start + i + 3];
        us8 v0 = f8[(size_t)t0 * LPN + lane];
        us8 v1 = f8[(size_t)t1 * LPN + lane];
        us8 v2 = f8[(size_t)t2 * LPN + lane];
        us8 v3 = f8[(size_t)t3 * LPN + lane];
        acc8(a, v0); acc8(a, v1); acc8(a, v2); acc8(a, v3);
    }
    for (; i < cnt; i++) {
        us8 v0 = f8[(size_t)csr[start + i] * LPN + lane];
        acc8(a, v0);
    }
    const float inv = 1.f / (float)(cnt > 0 ? cnt : 1);
    us8 w;
#pragma unroll
    for (int e = 0; e < 8; e++) w[e] = f2bf(a[e] * inv);
    reinterpret_cast<us8*>(aggout)[(size_t)n * LPN + lane] = w;
}

// ---------------- MFMA GEMM: out = act(A1@B1 + A2@B2 + bias), bf16 in/out, f32 acc ----

template <int K, bool RELU>
__global__ __launch_bounds__(256, 2) void gemm_mfma(
        const ushort* __restrict__ A1, const ushort* __restrict__ A2,
        const ushort* __restrict__ B1p, const ushort* __restrict__ B2p,
        const float* __restrict__ bias, ushort* __restrict__ out) {
    constexpr int KS = K / 32;
    __shared__ ushort Bs[2 * KS * 8 * 512];     // K=128: 64KB, K=64: 32KB
    const int tid = threadIdx.x;
    {   // stage both packed B matrices linearly into LDS
        const us8* g1 = reinterpret_cast<const us8*>(B1p);
        const us8* g2 = reinterpret_cast<const us8*>(B2p);
        us8* l8 = reinterpret_cast<us8*>(Bs);
        constexpr int PH = KS * 512;
#pragma unroll
        for (int i = 0; i < 4 * KS; i++) {
            int c = i * 256 + tid;
            if (i < 2 * KS) l8[c] = g1[c];
            else            l8[c] = g2[c - PH];
        }
    }
    __syncthreads();

    const int wave = tid >> 6, lane = tid & 63;
    const int r0 = blockIdx.x * 128 + wave * 32;
    const size_t arow = (size_t)(r0 + (lane & 15));
    const int koff = (lane >> 4) << 3;

    f4v acc[2][8];
#pragma unroll
    for (int rt = 0; rt < 2; rt++)
#pragma unroll
        for (int ct = 0; ct < 8; ct++) acc[rt][ct] = (f4v){0.f, 0.f, 0.f, 0.f};

    const s8v* Bf = reinterpret_cast<const s8v*>(Bs);
#pragma unroll
    for (int ph = 0; ph < 2; ph++) {
        const ushort* __restrict__ A = ph ? A2 : A1;
#pragma unroll
        for (int ks = 0; ks < KS; ks++) {
            s8v a0 = *reinterpret_cast<const s8v*>(A + arow * K + ks * 32 + koff);
            s8v a1 = *reinterpret_cast<const s8v*>(A + (arow + 16) * K + ks * 32 + koff);
#pragma unroll
            for (int ct = 0; ct < 8; ct++) {
                s8v b = Bf[((ph * KS + ks) * 8 + ct) * 64 + lane];
                acc[0][ct] = __builtin_amdgcn_mfma_f32_16x16x32_bf16(a0, b, acc[0][ct], 0, 0, 0);
                acc[1][ct] = __builtin_amdgcn_mfma_f32_16x16x32_bf16(a1, b, acc[1][ct], 0, 0, 0);
            }
        }
    }

    // epilogue: C/D layout col=lane&15, row=(lane>>4)*4+reg  [m89]
    const int colb = lane & 15;
    const int rowb = (lane >> 4) << 2;
#pragma unroll
    for (int rt = 0; rt < 2; rt++) {
#pragma unroll
        for (int ct = 0; ct < 8; ct++) {
            const int col = ct * 16 + colb;
            const float bb = bias[col];
#pragma unroll
            for (int j = 0; j < 4; j++) {
                int row = r0 + rt * 16 + rowb + j;
                if (row < N_NODES) {
                    float v = acc[rt][ct][j] + bb;
                    if (RELU) v = fmaxf(v, 0.f);
                    out[(size_t)row * HIDDEN + col] = f2bf(v);
                }
            }
        }
    }
}

// ------- edge_pool: per-graph-segment {edge-weighted sum of h2, plain node sum} -------
// Layer-3 + pool folded: mean_G(h3) = mean_G(agg3)@Wl3 + mean_G(h2)@Wr3 + bl3, and
// mean_G(agg3) = (1/|V_G|) sum_{d in V_G} (1/deg_d) sum_{s in N(d)} h2[s].
// 2048 blocks (512 graphs x 4 segments); same gather shape as aggregate_bf (16 lanes/node).

__global__ __launch_bounds__(256) void edge_pool(
        const ushort* __restrict__ h2, const int* __restrict__ batch,
        const int* __restrict__ cursor, const int* __restrict__ csr,
        float* __restrict__ Pe, float* __restrict__ Pn, int* __restrict__ gcnt) {
    const int blk = blockIdx.x;
    const int gid = blk >> 2, seg = blk & (PSEG - 1);
    __shared__ int sb[2];
    __shared__ float red[4][2][128];     // 4 KB
    const int tid = threadIdx.x;
    if (tid < 2) {
        int target = gid + tid;
        int lo = 0, hi = N_NODES;
        while (lo < hi) {
            int mid = (lo + hi) >> 1;
            if (batch[mid] < target) lo = mid + 1; else hi = mid;
        }
        sb[tid] = lo;
    }
    __syncthreads();
    const int s = sb[0], e = sb[1], len = e - s;
    const int per = (len + PSEG - 1) / PSEG;
    const int ss = s + seg * per;
    int ee = ss + per; if (ee > e) ee = e;

    const int ch  = tid & 15;            // 16B chunk (8 bf16) of the 128-dim row
    const int grp = tid >> 4;            // 16 node-groups
    const us8* __restrict__ f8 = reinterpret_cast<const us8*>(h2);
    float pe[8] = {0.f, 0.f, 0.f, 0.f, 0.f, 0.f, 0.f, 0.f};
    float pn[8] = {0.f, 0.f, 0.f, 0.f, 0.f, 0.f, 0.f, 0.f};

    for (int n = ss + grp; n < ee; n += 16) {
        const int start = n * MAXDEG;
        int cnt = cursor[n];
        if (cnt > MAXDEG) cnt = MAXDEG;
        float a[8] = {0.f, 0.f, 0.f, 0.f, 0.f, 0.f, 0.f, 0.f};
        int i = 0;
        for (; i + 8 <= cnt; i += 8) {
            int t0 = csr[start + i + 0], t1 = csr[start + i + 1];
            int t2 = csr[start + i + 2], t3 = csr[start + i + 3];
            int t4 = csr[start + i + 4], t5 = csr[start + i + 5];
            int t6 = csr[start + i + 6], t7 = csr[start + i + 7];
            us8 v0 = f8[(size_t)t0 * 16 + ch];
            us8 v1 = f8[(size_t)t1 * 16 + ch];
            us8 v2 = f8[(size_t)t2 * 16 + ch];
            us8 v3 = f8[(size_t)t3 * 16 + ch];
            us8 v4 = f8[(size_t)t4 * 16 + ch];
            us8 v5 = f8[(size_t)t5 * 16 + ch];
            us8 v6 = f8[(size_t)t6 * 16 + ch];
            us8 v7 = f8[(size_t)t7 * 16 + ch];
            acc8(a, v0); acc8(a, v1); acc8(a, v2); acc8(a, v3);
            acc8(a, v4); acc8(a, v5); acc8(a, v6); acc8(a, v7);
        }
        for (; i + 4 <= cnt; i += 4) {
            int t0 = csr[start + i + 0], t1 = csr[start + i + 1];
            int t2 = csr[start + i + 2], t3 = csr[start + i + 3];
            us8 v0 = f8[(size_t)t0 * 16 + ch];
            us8 v1 = f8[(size_t)t1 * 16 + ch];
            us8 v2 = f8[(size_t)t2 * 16 + ch];
            us8 v3 = f8[(size_t)t3 * 16 + ch];
            acc8(a, v0); acc8(a, v1); acc8(a, v2); acc8(a, v3);
        }
        for (; i < cnt; i++) {
            us8 v0 = f8[(size_t)csr[start + i] * 16 + ch];
            acc8(a, v0);
        }
        const float inv = 1.f / (float)(cnt > 0 ? cnt : 1);
#pragma unroll
        for (int j = 0; j < 8; j++) pe[j] += a[j] * inv;
        us8 v = f8[(size_t)n * 16 + ch];
        acc8(pn, v);
    }

    // reduce the 4 node-groups within each wave (same chunk at lane&15)
#pragma unroll
    for (int j = 0; j < 8; j++) {
        pe[j] += __shfl_xor(pe[j], 16); pe[j] += __shfl_xor(pe[j], 32);
        pn[j] += __shfl_xor(pn[j], 16); pn[j] += __shfl_xor(pn[j], 32);
    }
    const int wave = tid >> 6, lane = tid & 63;
    if (lane < 16) {
#pragma unroll
        for (int j = 0; j < 8; j++) {
            red[wave][0][lane * 8 + j] = pe[j];
            red[wave][1][lane * 8 + j] = pn[j];
        }
    }
    __syncthreads();
    if (tid < 128) {
        float se = red[0][0][tid] + red[1][0][tid] + red[2][0][tid] + red[3][0][tid];
        float sn = red[0][1][tid] + red[1][1][tid] + red[2][1][tid] + red[3][1][tid];
        Pe[(size_t)blk * 128 + tid] = se;
        Pn[(size_t)blk * 128 + tid] = sn;
    }
    if (tid == 0 && seg == 0) gcnt[gid] = len;
}

// ------- head_fused: g = Pe_mean@Wl3 + Pn_mean@Wr3 + bl3; out = g@W_out + b_out -------

__global__ __launch_bounds__(128) void head_fused(
        const float* __restrict__ Pe, const float* __restrict__ Pn,
        const int* __restrict__ gcnt,
        const float* __restrict__ Wl3, const float* __restrict__ Wr3,
        const float* __restrict__ bl3,
        const float* __restrict__ Wout, const float* __restrict__ bout,
        float* __restrict__ out) {
    const int gid = blockIdx.x, c = threadIdx.x;
    __shared__ float lse[128], lsn[128], lg[128];
    float se = 0.f, sn = 0.f;
#pragma unroll
    for (int sg = 0; sg < PSEG; sg++) {
        se += Pe[(size_t)(gid * PSEG + sg) * 128 + c];
        sn += Pn[(size_t)(gid * PSEG + sg) * 128 + c];
    }
    const int len = gcnt[gid];
    const float inv = 1.f / (float)(len > 0 ? len : 1);
    lse[c] = se * inv;
    lsn[c] = sn * inv;
    __syncthreads();
    float acc = (len > 0) ? bl3[c] : 0.f;
    for (int k = 0; k < 128; k++)
        acc += lse[k] * Wl3[k * 128 + c] + lsn[k] * Wr3[k * 128 + c];
    lg[c] = acc;
    __syncthreads();
    if (c < N_CLASSES) {
        float o = bout[c];
        for (int k = 0; k < 128; k++) o += lg[k] * Wout[k * N_CLASSES + c];
        out[(size_t)gid * N_CLASSES + c] = o;
    }
}

// ---------------- launch ----------------

extern "C" void kernel_launch(void* const* d_in, const int* in_sizes, int n_in,
                              void* d_out, int out_size, void* d_ws, size_t ws_size,
                              hipStream_t stream) {
    const float* x    = (const float*)d_in[0];
    const int* eidx   = (const int*)d_in[1];
    const int* batch  = (const int*)d_in[2];
    const float* Wl1  = (const float*)d_in[3];
    const float* bl1  = (const float*)d_in[4];
    const float* Wr1  = (const float*)d_in[5];
    const float* Wl2  = (const float*)d_in[6];
    const float* bl2  = (const float*)d_in[7];
    const float* Wr2  = (const float*)d_in[8];
    const float* Wl3  = (const float*)d_in[9];
    const float* bl3  = (const float*)d_in[10];
    const float* Wr3  = (const float*)d_in[11];
    const float* Wout = (const float*)d_in[12];
    const float* bout = (const float*)d_in[13];
    float* out = (float*)d_out;

    const int* esrc = eidx;
    const int* edst = eidx + N_EDGES;

    char* ws = (char*)d_ws;
    size_t o = 0;
    int*  bin_cursor = (int*)(ws + o);  o += 256 * 4;                        // zeroed
    int*  cursor     = (int*)(ws + o);  o += (size_t)N_NODES_B * 4;
    int*  csr        = (int*)(ws + o);  o += (size_t)N_NODES_B * MAXDEG * 4; // 25.7 MB
    int2* binbuf     = (int2*)(ws + o); o += (size_t)NBINS * BINCAP * 8;     // 14.1 MB
    o = (o + 255) & ~(size_t)255;
    ushort* xh   = (ushort*)(ws + o); o += (size_t)N_PAD * IN_FEAT * 2;
    ushort* aggb = (ushort*)(ws + o); o += (size_t)N_PAD * HIDDEN * 2;
    ushort* h1b  = (ushort*)(ws + o); o += (size_t)N_PAD * HIDDEN * 2;
    ushort* h2b  = (ushort*)(ws + o); o += (size_t)N_PAD * HIDDEN * 2;
    ushort* Bpk  = (ushort*)(ws + o); o += (size_t)49152 * 2;
    float*  Pe   = (float*)(ws + o);  o += (size_t)N_GRAPHS * PSEG * 128 * 4;
    float*  Pn   = (float*)(ws + o);  o += (size_t)N_GRAPHS * PSEG * 128 * 4;
    int*    gcnt = (int*)(ws + o);    o += (size_t)N_GRAPHS * 4;

    hipMemsetAsync(bin_cursor, 0, 256 * 4, stream);

    bin_kernel<<<(N_EDGES + EPB - 1) / EPB, 512, 0, stream>>>(esrc, edst, bin_cursor, binbuf);
    build_kernel<<<NBINS, 512, 0, stream>>>(binbuf, bin_cursor, cursor, csr);

    pack_weights_kernel<<<192, 256, 0, stream>>>(Wl1, Wr1, Wl2, Wr2, Bpk);
    convert_x_kernel<<<(N_PAD * IN_FEAT / 8) / 256, 256, 0, stream>>>(x, xh);

    ushort* Wl1p = Bpk + 0,     *Wr1p = Bpk + 8192;
    ushort* Wl2p = Bpk + 16384, *Wr2p = Bpk + 32768;

    const int GB = N_PAD / 128;                       // 782

    // layer 1
    aggregate_bf<IN_FEAT><<<(N_NODES + 31) / 32, 256, 0, stream>>>(xh, cursor, csr, aggb);
    gemm_mfma<IN_FEAT, true><<<GB, 256, 0, stream>>>(aggb, xh, Wl1p, Wr1p, bl1, h1b);
    // layer 2
    aggregate_bf<HIDDEN><<<(N_NODES + 15) / 16, 256, 0, stream>>>(h1b, cursor, csr, aggb);
    gemm_mfma<HIDDEN, true><<<GB, 256, 0, stream>>>(aggb, h1b, Wl2p, Wr2p, bl2, h2b);
    // layer 3 + pool folded: per-graph edge-weighted sum + node sum of h2
    edge_pool<<<N_GRAPHS * PSEG, 256, 0, stream>>>(h2b, batch, cursor, csr, Pe, Pn, gcnt);
    // g = Pe_mean@Wl3 + Pn_mean@Wr3 + bl3 ; out = g@W_out + b_out
    head_fused<<<N_GRAPHS, 128, 0, stream>>>(Pe, Pn, gcnt, Wl3, Wr3, bl3, Wout, bout, out);
}